// Round 5
// baseline (43972.800 us; speedup 1.0000x reference)
//
#include <hip/hip_runtime.h>
#include <math.h>

#define BB 8
#define TT 64
#define NN 256
#define HH 256
#define BN 2048
#define LSTR 72   // LDS row stride in ushorts for a 64-wide K chunk
#define NBLK 256  // persistent grid size

typedef float f32x4 __attribute__((ext_vector_type(4)));
typedef short s16x8 __attribute__((ext_vector_type(8)));

#define MFMA(a, b, c) __builtin_amdgcn_mfma_f32_16x16x32_bf16(a, b, c, 0, 0, 0)

__device__ __forceinline__ ushort rne_bf16(float x) {
    unsigned u = __builtin_bit_cast(unsigned, x);
    unsigned r = u + 0x7FFFu + ((u >> 16) & 1u);
    return (ushort)(r >> 16);
}
__device__ __forceinline__ float bf16_f32(ushort h) {
    unsigned u = ((unsigned)h) << 16;
    return __builtin_bit_cast(float, u);
}
__device__ __forceinline__ void split2(float x, ushort& hi, ushort& lo) {
    ushort h = rne_bf16(x);
    hi = h;
    lo = rne_bf16(x - bf16_f32(h));
}

// ---------------------------------------------------------------------------
// Distributed flag barrier with EXPLICIT cross-XCD cache maintenance.
// Release: drain vmem, write back dirty L2 (cross-XCD coherence point),
//          wait for wb completion, THEN publish flag (agent-scope atomic).
// Wait:    relaxed spin on flags[tid] (1:1 thread->block, atomics bypass L2).
// Acquire: invalidate L1/L2 so subsequent plain loads see producers' data.
// ---------------------------------------------------------------------------
__device__ __forceinline__ void gbar(unsigned* flags, unsigned gen, int bid, int tid) {
    __threadfence();
    asm volatile("s_waitcnt vmcnt(0) lgkmcnt(0)\n\t"
                 "buffer_wbl2 sc1\n\t"
                 "s_waitcnt vmcnt(0)" ::: "memory");
    __syncthreads();
    if (tid == 0)
        __hip_atomic_store(&flags[bid], gen, __ATOMIC_RELEASE, __HIP_MEMORY_SCOPE_AGENT);
    while (__hip_atomic_load(&flags[tid], __ATOMIC_RELAXED, __HIP_MEMORY_SCOPE_AGENT) < gen)
        __builtin_amdgcn_s_sleep(1);
    asm volatile("buffer_inv sc1\n\t"
                 "s_waitcnt vmcnt(0)" ::: "memory");
    __syncthreads();
    __threadfence();
}

// ---------------------------------------------------------------------------
struct Ctx {
    const float *x2d, *mask, *A, *Wx0, *Wh0, *b0, *Wx1, *Wh1, *b1, *Wout, *bout;
    float* out;
    float *h0, *h1, *z0, *z1, *Ax0All;
    ushort *h0Thi, *h0Tlo, *h1Thi, *h1Tlo;
    ushort *AhAhi, *AhAlo, *AhBhi, *AhBlo, *Ax1hi, *Ax1lo, *rhThi, *rhTlo;
    ushort *Abf, *WzrT0, *WcT0, *WxzrT1, *WhzrT1, *WxcT1, *WhcT1;
    unsigned* flags;
};

// ---------------------------------------------------------------------------
// prep element: round A to bf16; build transposed bf16 weight slabs [col][256]
// ---------------------------------------------------------------------------
__device__ __forceinline__ void dev_prep(int idx, const Ctx& c) {
    if (idx < 65536) { c.Abf[idx] = rne_bf16(c.A[idx]); return; }
    int e = idx - 65536;
    ushort* dst; const float* src; int colOff;
    if      (e < 131072) { dst = c.WzrT0;  src = c.Wh0; colOff = 0;   }
    else if (e < 196608) { dst = c.WcT0;   src = c.Wh0; colOff = 512; e -= 131072; }
    else if (e < 327680) { dst = c.WxzrT1; src = c.Wx1; colOff = 0;   e -= 196608; }
    else if (e < 458752) { dst = c.WhzrT1; src = c.Wh1; colOff = 0;   e -= 327680; }
    else if (e < 524288) { dst = c.WxcT1;  src = c.Wx1; colOff = 512; e -= 458752; }
    else                 { dst = c.WhcT1;  src = c.Wh1; colOff = 512; e -= 524288; }
    int col = e >> 8, k = e & 255;
    dst[e] = rne_bf16(src[k * 768 + colOff + col]);
}

// ---------------------------------------------------------------------------
// x-job: Ax0All[t] rows = A @ (x_t * mask_t), exact fp32. job in [0,2048)
// ---------------------------------------------------------------------------
__device__ void dev_xjob(int job, int tid, float* xs, float* red, const Ctx& c) {
    int t = job >> 5, lb = job & 31;
    int b = lb >> 2, rt = lb & 3;
    float* Ax0 = c.Ax0All + (size_t)t * 16384;
    const float* xbase = c.x2d + ((size_t)(b * TT + t) * NN) * 6;
    const float* mbase = c.mask + (size_t)(b * TT + t) * NN;
    {
        int m = tid;
        float mk = mbase[m];
        #pragma unroll
        for (int d = 0; d < 6; ++d) xs[m * 8 + d] = xbase[m * 6 + d] * mk;
    }
    __syncthreads();
    int i = tid & 63, q = tid >> 6;
    const float* arow = c.A + (size_t)(rt * 64 + i) * 256 + q * 64;
    float a6[6] = {0.f, 0.f, 0.f, 0.f, 0.f, 0.f};
    for (int m = 0; m < 64; ++m) {
        float a = arow[m];
        const float* xv = &xs[(q * 64 + m) * 8];
        #pragma unroll
        for (int d = 0; d < 6; ++d) a6[d] = fmaf(a, xv[d], a6[d]);
    }
    #pragma unroll
    for (int d = 0; d < 6; ++d) red[(i * 4 + q) * 8 + d] = a6[d];
    __syncthreads();
    for (int idx2 = tid; idx2 < 64 * 6; idx2 += 256) {
        int ii = idx2 / 6, d = idx2 - ii * 6;
        float s = red[(ii * 4 + 0) * 8 + d] + red[(ii * 4 + 1) * 8 + d]
                + red[(ii * 4 + 2) * 8 + d] + red[(ii * 4 + 3) * 8 + d];
        Ax0[(size_t)(b * 256 + rt * 64 + ii) * 8 + d] = s;
    }
    __syncthreads();
}

// ---------------------------------------------------------------------------
// head: out[b,t,n,:] = h1[row,:] @ Wout + bout.  lb in [0,72)
// ---------------------------------------------------------------------------
__device__ void dev_head(int lb, int tid, const Ctx& c, int tprev) {
    int g = lb * 256 + tid;
    int row = g / 9, o = g - row * 9;
    if (row >= BN) return;
    const float* hr = c.h1 + (size_t)row * 256;
    float s = c.bout[o];
    for (int k = 0; k < 256; k += 4) {
        float4 hv = *(const float4*)(hr + k);
        s = fmaf(hv.x, c.Wout[(k + 0) * 9 + o], s);
        s = fmaf(hv.y, c.Wout[(k + 1) * 9 + o], s);
        s = fmaf(hv.z, c.Wout[(k + 2) * 9 + o], s);
        s = fmaf(hv.w, c.Wout[(k + 3) * 9 + o], s);
    }
    int b = row >> 8, n = row & 255;
    c.out[((size_t)(b * TT + tprev) * NN + n) * 9 + o] = s;
}

// ---------------------------------------------------------------------------
// A-apply via MFMA: Y(split pair, rows) = A_bf16 @ XT(split pair). lb in [0,128)
// ---------------------------------------------------------------------------
__device__ void dev_aapply(int lb, int tid, ushort* lds, const ushort* Abf,
    const ushort* XThi, const ushort* XTlo, ushort* Yhi, ushort* Ylo)
{
    ushort* As   = lds;
    ushort* Bshi = lds + 64 * LSTR;
    ushort* Bslo = lds + 2 * 64 * LSTR;
    const int b = lb >> 4, rt = (lb >> 2) & 3, ct = lb & 3;
    const int lane = tid & 63, wave = tid >> 6;
    const int wr = wave >> 1, wc = wave & 1;
    const int l15 = lane & 15, q8 = (lane >> 4) << 3;

    f32x4 acc[2][2];
    acc[0][0] = 0.f; acc[0][1] = 0.f; acc[1][0] = 0.f; acc[1][1] = 0.f;

    const int rr = tid >> 2, ko = (tid & 3) << 4;
    const ushort* Asrc = Abf + (size_t)(rt * 64 + rr) * 256 + ko;
    const ushort* Bh   = XThi + (size_t)(b * 256 + ct * 64 + rr) * 256 + ko;
    const ushort* Bl   = XTlo + (size_t)(b * 256 + ct * 64 + rr) * 256 + ko;
    ushort* wA = &As[rr * LSTR + ko];
    ushort* wH = &Bshi[rr * LSTR + ko];
    ushort* wL = &Bslo[rr * LSTR + ko];

    for (int k0 = 0; k0 < 256; k0 += 64) {
        __syncthreads();
        *(uint4*)(wA)     = *(const uint4*)(Asrc + k0);
        *(uint4*)(wA + 8) = *(const uint4*)(Asrc + k0 + 8);
        *(uint4*)(wH)     = *(const uint4*)(Bh + k0);
        *(uint4*)(wH + 8) = *(const uint4*)(Bh + k0 + 8);
        *(uint4*)(wL)     = *(const uint4*)(Bl + k0);
        *(uint4*)(wL + 8) = *(const uint4*)(Bl + k0 + 8);
        __syncthreads();
        #pragma unroll
        for (int sub = 0; sub < 2; ++sub) {
            const int kb = sub * 32 + q8;
            s16x8 a0  = *(const s16x8*)&As[(wr * 32 + l15) * LSTR + kb];
            s16x8 a1  = *(const s16x8*)&As[(wr * 32 + 16 + l15) * LSTR + kb];
            s16x8 bh0 = *(const s16x8*)&Bshi[(wc * 32 + l15) * LSTR + kb];
            s16x8 bh1 = *(const s16x8*)&Bshi[(wc * 32 + 16 + l15) * LSTR + kb];
            s16x8 bl0 = *(const s16x8*)&Bslo[(wc * 32 + l15) * LSTR + kb];
            s16x8 bl1 = *(const s16x8*)&Bslo[(wc * 32 + 16 + l15) * LSTR + kb];
            acc[0][0] = MFMA(a0, bh0, acc[0][0]);
            acc[0][0] = MFMA(a0, bl0, acc[0][0]);
            acc[0][1] = MFMA(a0, bh1, acc[0][1]);
            acc[0][1] = MFMA(a0, bl1, acc[0][1]);
            acc[1][0] = MFMA(a1, bh0, acc[1][0]);
            acc[1][0] = MFMA(a1, bl0, acc[1][0]);
            acc[1][1] = MFMA(a1, bh1, acc[1][1]);
            acc[1][1] = MFMA(a1, bl1, acc[1][1]);
        }
    }
    const int quad = lane >> 4;
    #pragma unroll
    for (int i = 0; i < 2; ++i) {
        #pragma unroll
        for (int j = 0; j < 2; ++j) {
            const int col = ct * 64 + wc * 32 + j * 16 + l15;
            const int m0  = rt * 64 + wr * 32 + i * 16 + quad * 4;
            const size_t base = (size_t)(b * 256 + m0) * 256 + col;
            #pragma unroll
            for (int r = 0; r < 4; ++r) {
                ushort hi, lo;
                split2(acc[i][j][r], hi, lo);
                Yhi[base + (size_t)r * 256] = hi;
                Ylo[base + (size_t)r * 256] = lo;
            }
        }
    }
}

// ---------------------------------------------------------------------------
// wact: gate GEMM (dynamic split pair x static bf16 WT) + gate epilogue
// ---------------------------------------------------------------------------
struct WAP {
    const ushort* Lhi0; const ushort* Llo0; const ushort* RT0;
    const ushort* Lhi1; const ushort* Llo1; const ushort* RT1;
    int ngemm;
    const float* bias;
    int useK6; int wxColOff;
    const float* Ax0; const float* Wx0;
    const float* h;
    float* z;
    float* hOut;
    ushort* Thi; ushort* Tlo;
    int mode;
};

__device__ void dev_wact(const WAP& p, int bid, int tid, ushort* lds) {
    ushort* Ashi = lds;
    ushort* Aslo = lds + 64 * LSTR;
    ushort* Bs   = lds + 2 * 64 * LSTR;
    int b, rt, ct;
    if (p.mode == 0) { b = bid >> 5; rt = (bid >> 3) & 3; ct = bid & 7; }
    else             { b = bid >> 4; rt = (bid >> 2) & 3; ct = bid & 3; }

    const int lane = tid & 63, wave = tid >> 6;
    const int wr = wave >> 1, wc = wave & 1;
    const int l15 = lane & 15, q8 = (lane >> 4) << 3;

    f32x4 acc[2][2];
    acc[0][0] = 0.f; acc[0][1] = 0.f; acc[1][0] = 0.f; acc[1][1] = 0.f;

    const int rr = tid >> 2, ko = (tid & 3) << 4;
    for (int g = 0; g < p.ngemm; ++g) {
        const ushort* Lh = (g ? p.Lhi1 : p.Lhi0) + (size_t)(b * 256 + rt * 64 + rr) * 256 + ko;
        const ushort* Ll = (g ? p.Llo1 : p.Llo0) + (size_t)(b * 256 + rt * 64 + rr) * 256 + ko;
        const ushort* Rt = (g ? p.RT1  : p.RT0 ) + (size_t)(ct * 64 + rr) * 256 + ko;
        ushort* wA = &Ashi[rr * LSTR + ko];
        ushort* wL = &Aslo[rr * LSTR + ko];
        ushort* wB = &Bs[rr * LSTR + ko];
        for (int k0 = 0; k0 < 256; k0 += 64) {
            __syncthreads();
            *(uint4*)(wA)     = *(const uint4*)(Lh + k0);
            *(uint4*)(wA + 8) = *(const uint4*)(Lh + k0 + 8);
            *(uint4*)(wL)     = *(const uint4*)(Ll + k0);
            *(uint4*)(wL + 8) = *(const uint4*)(Ll + k0 + 8);
            *(uint4*)(wB)     = *(const uint4*)(Rt + k0);
            *(uint4*)(wB + 8) = *(const uint4*)(Rt + k0 + 8);
            __syncthreads();
            #pragma unroll
            for (int sub = 0; sub < 2; ++sub) {
                const int kb = sub * 32 + q8;
                s16x8 ah0 = *(const s16x8*)&Ashi[(wr * 32 + l15) * LSTR + kb];
                s16x8 ah1 = *(const s16x8*)&Ashi[(wr * 32 + 16 + l15) * LSTR + kb];
                s16x8 al0 = *(const s16x8*)&Aslo[(wr * 32 + l15) * LSTR + kb];
                s16x8 al1 = *(const s16x8*)&Aslo[(wr * 32 + 16 + l15) * LSTR + kb];
                s16x8 b0  = *(const s16x8*)&Bs[(wc * 32 + l15) * LSTR + kb];
                s16x8 b1  = *(const s16x8*)&Bs[(wc * 32 + 16 + l15) * LSTR + kb];
                acc[0][0] = MFMA(ah0, b0, acc[0][0]);
                acc[0][0] = MFMA(al0, b0, acc[0][0]);
                acc[0][1] = MFMA(ah0, b1, acc[0][1]);
                acc[0][1] = MFMA(al0, b1, acc[0][1]);
                acc[1][0] = MFMA(ah1, b0, acc[1][0]);
                acc[1][0] = MFMA(al1, b0, acc[1][0]);
                acc[1][1] = MFMA(ah1, b1, acc[1][1]);
                acc[1][1] = MFMA(al1, b1, acc[1][1]);
            }
        }
    }

    const int quad = lane >> 4;
    const int m0base = rt * 64 + wr * 32;
    int colg[2];
    #pragma unroll
    for (int j = 0; j < 2; ++j) colg[j] = ct * 64 + wc * 32 + j * 16 + l15;
    float bv[2] = { p.bias[colg[0]], p.bias[colg[1]] };
    float v[2][2][4];
    #pragma unroll
    for (int i = 0; i < 2; ++i)
        #pragma unroll
        for (int j = 0; j < 2; ++j)
            #pragma unroll
            for (int r = 0; r < 4; ++r)
                v[i][j][r] = acc[i][j][r] + bv[j];

    if (p.useK6) {
        float w6[2][6];
        #pragma unroll
        for (int j = 0; j < 2; ++j)
            #pragma unroll
            for (int d = 0; d < 6; ++d)
                w6[j][d] = p.Wx0[d * 768 + p.wxColOff + colg[j]];
        #pragma unroll
        for (int i = 0; i < 2; ++i) {
            #pragma unroll
            for (int r = 0; r < 4; ++r) {
                int row = b * 256 + m0base + i * 16 + quad * 4 + r;
                const float* ax = p.Ax0 + (size_t)row * 8;
                float a0 = ax[0], a1 = ax[1], a2 = ax[2], a3 = ax[3], a4 = ax[4], a5 = ax[5];
                #pragma unroll
                for (int j = 0; j < 2; ++j)
                    v[i][j][r] += a0 * w6[j][0] + a1 * w6[j][1] + a2 * w6[j][2]
                                + a3 * w6[j][3] + a4 * w6[j][4] + a5 * w6[j][5];
            }
        }
    }

    if (p.mode == 0) {
        if (ct < 4) {
            #pragma unroll
            for (int i = 0; i < 2; ++i)
                #pragma unroll
                for (int r = 0; r < 4; ++r) {
                    int row = b * 256 + m0base + i * 16 + quad * 4 + r;
                    #pragma unroll
                    for (int j = 0; j < 2; ++j)
                        p.z[(size_t)row * 256 + colg[j]] = 1.f / (1.f + __expf(-v[i][j][r]));
                }
        } else {
            #pragma unroll
            for (int i = 0; i < 2; ++i) {
                int m0 = m0base + i * 16 + quad * 4;
                #pragma unroll
                for (int j = 0; j < 2; ++j) {
                    int colp = colg[j] - 256;
                    ushort hi4[4], lo4[4];
                    #pragma unroll
                    for (int r = 0; r < 4; ++r) {
                        int row = b * 256 + m0 + r;
                        float s = 1.f / (1.f + __expf(-v[i][j][r]));
                        float rh = s * p.h[(size_t)row * 256 + colp];
                        split2(rh, hi4[r], lo4[r]);
                    }
                    size_t off = (size_t)b * 65536 + (size_t)colp * 256 + m0;
                    *(ushort4*)&p.Thi[off] = make_ushort4(hi4[0], hi4[1], hi4[2], hi4[3]);
                    *(ushort4*)&p.Tlo[off] = make_ushort4(lo4[0], lo4[1], lo4[2], lo4[3]);
                }
            }
        }
    } else {
        #pragma unroll
        for (int i = 0; i < 2; ++i) {
            int m0 = m0base + i * 16 + quad * 4;
            #pragma unroll
            for (int j = 0; j < 2; ++j) {
                ushort hi4[4], lo4[4];
                #pragma unroll
                for (int r = 0; r < 4; ++r) {
                    int row = b * 256 + m0 + r;
                    size_t gi = (size_t)row * 256 + colg[j];
                    float cc = tanhf(v[i][j][r]);
                    float zz = p.z[gi];
                    float hh = p.h[gi];
                    float hn = zz * hh + (1.f - zz) * cc;
                    p.hOut[gi] = hn;
                    split2(hn, hi4[r], lo4[r]);
                }
                size_t off = (size_t)b * 65536 + (size_t)colg[j] * 256 + m0;
                *(ushort4*)&p.Thi[off] = make_ushort4(hi4[0], hi4[1], hi4[2], hi4[3]);
                *(ushort4*)&p.Tlo[off] = make_ushort4(lo4[0], lo4[1], lo4[2], lo4[3]);
            }
        }
    }
}

// ---------------------------------------------------------------------------
// Persistent kernel: whole recurrence, flag barriers between phases.
// ---------------------------------------------------------------------------
__global__ __launch_bounds__(256) void persist_kernel(Ctx c) {
    __shared__ ushort lds[3 * 64 * LSTR];
    const int tid = threadIdx.x, bid = blockIdx.x;
    unsigned gen = 0;

    // prologue: weight prep + all x-jobs (input-only dependencies)
    for (int i = bid * 256 + tid; i < 655360; i += NBLK * 256) dev_prep(i, c);
    for (int j = bid; j < 2048; j += NBLK)
        dev_xjob(j, tid, (float*)lds, ((float*)lds) + 2048, c);
    gbar(c.flags, ++gen, bid, tid);

    for (int t = 0; t < TT; ++t) {
        const float* Ax0t = c.Ax0All + (size_t)t * 16384;
        // k1: Ah0 = A@h0 (128 jobs) + head(t-1) (72 jobs)
        if (bid < 128) dev_aapply(bid, tid, lds, c.Abf, c.h0Thi, c.h0Tlo, c.AhAhi, c.AhAlo);
        else if (bid < 200 && t > 0) dev_head(bid - 128, tid, c, t - 1);
        gbar(c.flags, ++gen, bid, tid);
        // k2: z0, rh0T (256 jobs)
        { WAP p{c.AhAhi, c.AhAlo, c.WzrT0, nullptr, nullptr, nullptr, 1,
                c.b0, 1, 0, Ax0t, c.Wx0, c.h0, c.z0, nullptr, c.rhThi, c.rhTlo, 0};
          dev_wact(p, bid, tid, lds); }
        gbar(c.flags, ++gen, bid, tid);
        // k3: Arh0 = A@rh0T (128 jobs)
        if (bid < 128) dev_aapply(bid, tid, lds, c.Abf, c.rhThi, c.rhTlo, c.AhAhi, c.AhAlo);
        gbar(c.flags, ++gen, bid, tid);
        // k4: h0 update (+h0T) (128 jobs)
        if (bid < 128) {
            WAP p{c.AhAhi, c.AhAlo, c.WcT0, nullptr, nullptr, nullptr, 1,
                  c.b0 + 512, 1, 512, Ax0t, c.Wx0, c.h0, c.z0, c.h0, c.h0Thi, c.h0Tlo, 1};
            dev_wact(p, bid, tid, lds);
        }
        gbar(c.flags, ++gen, bid, tid);
        // k5: Ax1 = A@h0T (128) + Ah1 = A@h1T (128)
        if (bid < 128) dev_aapply(bid, tid, lds, c.Abf, c.h0Thi, c.h0Tlo, c.Ax1hi, c.Ax1lo);
        else dev_aapply(bid - 128, tid, lds, c.Abf, c.h1Thi, c.h1Tlo, c.AhBhi, c.AhBlo);
        gbar(c.flags, ++gen, bid, tid);
        // k6: z1, rh1T (256 jobs)
        { WAP p{c.Ax1hi, c.Ax1lo, c.WxzrT1, c.AhBhi, c.AhBlo, c.WhzrT1, 2,
                c.b1, 0, 0, Ax0t, c.Wx0, c.h1, c.z1, nullptr, c.rhThi, c.rhTlo, 0};
          dev_wact(p, bid, tid, lds); }
        gbar(c.flags, ++gen, bid, tid);
        // k7: Arh1 = A@rh1T (128 jobs)
        if (bid < 128) dev_aapply(bid, tid, lds, c.Abf, c.rhThi, c.rhTlo, c.AhBhi, c.AhBlo);
        gbar(c.flags, ++gen, bid, tid);
        // k8: h1 update (+h1T) (128 jobs)
        if (bid < 128) {
            WAP p{c.AhBhi, c.AhBlo, c.WhcT1, c.Ax1hi, c.Ax1lo, c.WxcT1, 2,
                  c.b1 + 512, 0, 0, Ax0t, c.Wx0, c.h1, c.z1, c.h1, c.h1Thi, c.h1Tlo, 1};
            dev_wact(p, bid, tid, lds);
        }
        gbar(c.flags, ++gen, bid, tid);
    }
    // final head (t = 63); last k8 barrier already passed
    if (bid < 72) dev_head(bid, tid, c, TT - 1);
}

// ---------------------------------------------------------------------------
extern "C" void kernel_launch(void* const* d_in, const int* in_sizes, int n_in,
                              void* d_out, int out_size, void* d_ws, size_t ws_size,
                              hipStream_t stream) {
    const size_t SZ = (size_t)BN * HH;   // 524288
    float* ws = (float*)d_ws;

    Ctx c;
    c.x2d  = (const float*)d_in[0];
    c.mask = (const float*)d_in[1];
    c.A    = (const float*)d_in[2];
    c.Wx0  = (const float*)d_in[3];
    c.Wh0  = (const float*)d_in[4];
    c.b0   = (const float*)d_in[5];
    c.Wx1  = (const float*)d_in[6];
    c.Wh1  = (const float*)d_in[7];
    c.b1   = (const float*)d_in[8];
    c.Wout = (const float*)d_in[9];
    c.bout = (const float*)d_in[10];
    c.out  = (float*)d_out;

    c.h0    = ws;                 // SZ
    c.h1    = ws + SZ;            // SZ
    c.h0Thi = (ushort*)(ws + 2 * SZ);
    c.h0Tlo = c.h0Thi + SZ;
    c.h1Thi = c.h0Tlo + SZ;
    c.h1Tlo = c.h1Thi + SZ;       // ends at ws + 4*SZ (float units)
    c.flags = (unsigned*)(ws + 4 * SZ);   // 256 uints
    c.z0    = ws + 4 * SZ + 256;
    c.z1    = c.z0 + SZ;
    c.Ax0All = c.z1 + SZ;         // 64 * 16384 = 2*SZ floats (4 MB)
    c.AhAhi = (ushort*)(c.Ax0All + 2 * SZ);
    c.AhAlo = c.AhAhi + SZ;
    c.AhBhi = c.AhAlo + SZ;
    c.AhBlo = c.AhBhi + SZ;
    c.Ax1hi = c.AhBlo + SZ;
    c.Ax1lo = c.Ax1hi + SZ;
    c.rhThi = c.Ax1lo + SZ;
    c.rhTlo = c.rhThi + SZ;
    c.Abf   = c.rhTlo + SZ;       // 65536
    c.WzrT0 = c.Abf + 65536;      // 131072
    c.WcT0  = c.WzrT0 + 131072;   // 65536
    c.WxzrT1 = c.WcT0 + 65536;    // 131072
    c.WhzrT1 = c.WxzrT1 + 131072; // 131072
    c.WxcT1  = c.WhzrT1 + 131072; // 65536
    c.WhcT1  = c.WxcT1 + 65536;   // 65536

    // zero h0,h1 (fp32), h0T/h1T split pairs (bf16 zero = 0), barrier flags
    hipMemsetAsync(ws, 0, (4 * SZ + 256) * sizeof(float), stream);

    persist_kernel<<<dim3(NBLK), dim3(256), 0, stream>>>(c);
}

// Round 6
// 10738.037 us; speedup vs baseline: 4.0951x; 4.0951x over previous
//
#include <hip/hip_runtime.h>
#include <math.h>

#define BB 8
#define TT 64
#define NN 256
#define HH 256
#define BN 2048
#define LSTR 72   // LDS row stride in ushorts for a 64-wide K chunk
#define NBLK 256  // persistent grid size

typedef float f32x4 __attribute__((ext_vector_type(4)));
typedef short s16x8 __attribute__((ext_vector_type(8)));

#define MFMA(a, b, c) __builtin_amdgcn_mfma_f32_16x16x32_bf16(a, b, c, 0, 0, 0)

__device__ __forceinline__ ushort rne_bf16(float x) {
    unsigned u = __builtin_bit_cast(unsigned, x);
    unsigned r = u + 0x7FFFu + ((u >> 16) & 1u);
    return (ushort)(r >> 16);
}
__device__ __forceinline__ float bf16_f32(ushort h) {
    unsigned u = ((unsigned)h) << 16;
    return __builtin_bit_cast(float, u);
}
__device__ __forceinline__ void split2(float x, ushort& hi, ushort& lo) {
    ushort h = rne_bf16(x);
    hi = h;
    lo = rne_bf16(x - bf16_f32(h));
}

// ---------------------------------------------------------------------------
// Coherent transport primitives.
// Stores: inline asm sc0+sc1 (write-through to the agent coherence point,
// fire-and-forget; drained by s_waitcnt vmcnt(0) at barrier arrival).
// Loads: relaxed agent-scope atomics -> global_load ... sc1, snooping the
// coherence point, with compiler-tracked vmcnt so independent loads pipeline.
// Static data (weights, A, inputs) keeps plain cached loads and stays hot in
// L2 because nothing invalidates caches anymore.
// ---------------------------------------------------------------------------
__device__ __forceinline__ void st_u16(ushort* p, ushort v) {
    asm volatile("global_store_short %0, %1, off sc0 sc1" :: "v"(p), "v"((unsigned)v) : "memory");
}
__device__ __forceinline__ void st_u32(void* p, unsigned v) {
    asm volatile("global_store_dword %0, %1, off sc0 sc1" :: "v"(p), "v"(v) : "memory");
}
__device__ __forceinline__ void st_f32(float* p, float v) {
    st_u32((void*)p, __builtin_bit_cast(unsigned, v));
}
__device__ __forceinline__ void st_u64(void* p, unsigned long long v) {
    asm volatile("global_store_dwordx2 %0, %1, off sc0 sc1" :: "v"(p), "v"(v) : "memory");
}
__device__ __forceinline__ float ld_f32(const float* p) {
    unsigned u = __hip_atomic_load((const unsigned*)p, __ATOMIC_RELAXED, __HIP_MEMORY_SCOPE_AGENT);
    return __builtin_bit_cast(float, u);
}
__device__ __forceinline__ unsigned long long ld_u64(const void* p) {
    return __hip_atomic_load((const unsigned long long*)p, __ATOMIC_RELAXED, __HIP_MEMORY_SCOPE_AGENT);
}
__device__ __forceinline__ float2 u64_f2(unsigned long long v) {
    float2 r;
    r.x = __builtin_bit_cast(float, (unsigned)v);
    r.y = __builtin_bit_cast(float, (unsigned)(v >> 32));
    return r;
}
__device__ __forceinline__ unsigned long long pack4(const ushort* h) {
    return (unsigned long long)h[0] | ((unsigned long long)h[1] << 16)
         | ((unsigned long long)h[2] << 32) | ((unsigned long long)h[3] << 48);
}

// ---------------------------------------------------------------------------
// Distributed flag barrier. Data coherence is carried by the sc1 data ops
// themselves; the barrier only needs store-drain + flag propagation.
// ---------------------------------------------------------------------------
__device__ __forceinline__ void gbar(unsigned* flags, unsigned gen, int bid, int tid) {
    asm volatile("s_waitcnt vmcnt(0)" ::: "memory");
    __syncthreads();
    if (tid == 0)
        __hip_atomic_store(&flags[bid], gen, __ATOMIC_RELAXED, __HIP_MEMORY_SCOPE_AGENT);
    while (__hip_atomic_load(&flags[tid], __ATOMIC_RELAXED, __HIP_MEMORY_SCOPE_AGENT) < gen)
        __builtin_amdgcn_s_sleep(2);
    __syncthreads();
}

// ---------------------------------------------------------------------------
struct Ctx {
    const float *x2d, *mask, *A, *Wx0, *Wh0, *b0, *Wx1, *Wh1, *b1, *Wout, *bout;
    float* out;
    float *h0, *h1, *z0, *z1, *Ax0All;
    ushort *h0Thi, *h0Tlo, *h1Thi, *h1Tlo;
    ushort *AhAhi, *AhAlo, *AhBhi, *AhBlo, *Ax1hi, *Ax1lo, *rhThi, *rhTlo;
    ushort *Abf, *WzrT0, *WcT0, *WxzrT1, *WhzrT1, *WxcT1, *WhcT1;
    unsigned* flags;
};

// ---------------------------------------------------------------------------
// prep: round A to bf16; transposed bf16 weight slabs. One-time sc1 stores.
// ---------------------------------------------------------------------------
__device__ __forceinline__ void dev_prep(int idx, const Ctx& c) {
    if (idx < 65536) { st_u16(c.Abf + idx, rne_bf16(c.A[idx])); return; }
    int e = idx - 65536;
    ushort* dst; const float* src; int colOff;
    if      (e < 131072) { dst = c.WzrT0;  src = c.Wh0; colOff = 0;   }
    else if (e < 196608) { dst = c.WcT0;   src = c.Wh0; colOff = 512; e -= 131072; }
    else if (e < 327680) { dst = c.WxzrT1; src = c.Wx1; colOff = 0;   e -= 196608; }
    else if (e < 458752) { dst = c.WhzrT1; src = c.Wh1; colOff = 0;   e -= 327680; }
    else if (e < 524288) { dst = c.WxcT1;  src = c.Wx1; colOff = 512; e -= 458752; }
    else                 { dst = c.WhcT1;  src = c.Wh1; colOff = 512; e -= 524288; }
    int col = e >> 8, k = e & 255;
    st_u16(dst + e, rne_bf16(src[k * 768 + colOff + col]));
}

// ---------------------------------------------------------------------------
// x-job: Ax0All[t] = A @ (x_t * mask_t), exact fp32.  job in [0,2048)
// ---------------------------------------------------------------------------
__device__ void dev_xjob(int job, int tid, float* xs, float* red, const Ctx& c) {
    int t = job >> 5, lb = job & 31;
    int b = lb >> 2, rt = lb & 3;
    float* Ax0 = c.Ax0All + (size_t)t * 16384;
    const float* xbase = c.x2d + ((size_t)(b * TT + t) * NN) * 6;
    const float* mbase = c.mask + (size_t)(b * TT + t) * NN;
    {
        int m = tid;
        float mk = mbase[m];
        #pragma unroll
        for (int d = 0; d < 6; ++d) xs[m * 8 + d] = xbase[m * 6 + d] * mk;
    }
    __syncthreads();
    int i = tid & 63, q = tid >> 6;
    const float* arow = c.A + (size_t)(rt * 64 + i) * 256 + q * 64;
    float a6[6] = {0.f, 0.f, 0.f, 0.f, 0.f, 0.f};
    for (int m = 0; m < 64; ++m) {
        float a = arow[m];
        const float* xv = &xs[(q * 64 + m) * 8];
        #pragma unroll
        for (int d = 0; d < 6; ++d) a6[d] = fmaf(a, xv[d], a6[d]);
    }
    #pragma unroll
    for (int d = 0; d < 6; ++d) red[(i * 4 + q) * 8 + d] = a6[d];
    __syncthreads();
    for (int idx2 = tid; idx2 < 64 * 6; idx2 += 256) {
        int ii = idx2 / 6, d = idx2 - ii * 6;
        float s = red[(ii * 4 + 0) * 8 + d] + red[(ii * 4 + 1) * 8 + d]
                + red[(ii * 4 + 2) * 8 + d] + red[(ii * 4 + 3) * 8 + d];
        st_f32(Ax0 + (size_t)(b * 256 + rt * 64 + ii) * 8 + d, s);
    }
    __syncthreads();
}

// ---------------------------------------------------------------------------
// head: out[b,t,n,:] = h1[row,:] @ Wout + bout.  lb in [0,72)
// h1 read coherent (written by k8); Wout/bout cached; out plain (kernel-end flush).
// ---------------------------------------------------------------------------
__device__ void dev_head(int lb, int tid, const Ctx& c, int tprev) {
    int g = lb * 256 + tid;
    int row = g / 9, o = g - row * 9;
    if (row >= BN) return;
    const float* hr = c.h1 + (size_t)row * 256;
    float s = c.bout[o];
    #pragma unroll 8
    for (int k = 0; k < 256; k += 2) {
        float2 hv = u64_f2(ld_u64(hr + k));
        s = fmaf(hv.x, c.Wout[(k + 0) * 9 + o], s);
        s = fmaf(hv.y, c.Wout[(k + 1) * 9 + o], s);
    }
    int b = row >> 8, n = row & 255;
    c.out[((size_t)(b * TT + tprev) * NN + n) * 9 + o] = s;
}

// ---------------------------------------------------------------------------
// A-apply via MFMA: Y(split pair) = A_bf16 @ XT(split pair). lb in [0,128)
// A staged via cached loads (L2-hot); XT hi/lo via coherent u64 loads.
// ---------------------------------------------------------------------------
__device__ void dev_aapply(int lb, int tid, ushort* lds, const ushort* Abf,
    const ushort* XThi, const ushort* XTlo, ushort* Yhi, ushort* Ylo)
{
    ushort* As   = lds;
    ushort* Bshi = lds + 64 * LSTR;
    ushort* Bslo = lds + 2 * 64 * LSTR;
    const int b = lb >> 4, rt = (lb >> 2) & 3, ct = lb & 3;
    const int lane = tid & 63, wave = tid >> 6;
    const int wr = wave >> 1, wc = wave & 1;
    const int l15 = lane & 15, q8 = (lane >> 4) << 3;

    f32x4 acc[2][2];
    acc[0][0] = 0.f; acc[0][1] = 0.f; acc[1][0] = 0.f; acc[1][1] = 0.f;

    const int rr = tid >> 2, ko = (tid & 3) << 4;
    const ushort* Asrc = Abf + (size_t)(rt * 64 + rr) * 256 + ko;
    const ushort* Bh   = XThi + (size_t)(b * 256 + ct * 64 + rr) * 256 + ko;
    const ushort* Bl   = XTlo + (size_t)(b * 256 + ct * 64 + rr) * 256 + ko;
    ushort* wA = &As[rr * LSTR + ko];
    ushort* wH = &Bshi[rr * LSTR + ko];
    ushort* wL = &Bslo[rr * LSTR + ko];

    for (int k0 = 0; k0 < 256; k0 += 64) {
        unsigned long long hh[4], ll[4];
        #pragma unroll
        for (int q = 0; q < 4; ++q) hh[q] = ld_u64(Bh + k0 + 4 * q);
        #pragma unroll
        for (int q = 0; q < 4; ++q) ll[q] = ld_u64(Bl + k0 + 4 * q);
        uint4 a0 = *(const uint4*)(Asrc + k0);
        uint4 a1 = *(const uint4*)(Asrc + k0 + 8);
        __syncthreads();
        *(uint4*)(wA)     = a0;
        *(uint4*)(wA + 8) = a1;
        #pragma unroll
        for (int q = 0; q < 4; ++q) *(unsigned long long*)(wH + 4 * q) = hh[q];
        #pragma unroll
        for (int q = 0; q < 4; ++q) *(unsigned long long*)(wL + 4 * q) = ll[q];
        __syncthreads();
        #pragma unroll
        for (int sub = 0; sub < 2; ++sub) {
            const int kb = sub * 32 + q8;
            s16x8 a0f = *(const s16x8*)&As[(wr * 32 + l15) * LSTR + kb];
            s16x8 a1f = *(const s16x8*)&As[(wr * 32 + 16 + l15) * LSTR + kb];
            s16x8 bh0 = *(const s16x8*)&Bshi[(wc * 32 + l15) * LSTR + kb];
            s16x8 bh1 = *(const s16x8*)&Bshi[(wc * 32 + 16 + l15) * LSTR + kb];
            s16x8 bl0 = *(const s16x8*)&Bslo[(wc * 32 + l15) * LSTR + kb];
            s16x8 bl1 = *(const s16x8*)&Bslo[(wc * 32 + 16 + l15) * LSTR + kb];
            acc[0][0] = MFMA(a0f, bh0, acc[0][0]);
            acc[0][0] = MFMA(a0f, bl0, acc[0][0]);
            acc[0][1] = MFMA(a0f, bh1, acc[0][1]);
            acc[0][1] = MFMA(a0f, bl1, acc[0][1]);
            acc[1][0] = MFMA(a1f, bh0, acc[1][0]);
            acc[1][0] = MFMA(a1f, bl0, acc[1][0]);
            acc[1][1] = MFMA(a1f, bh1, acc[1][1]);
            acc[1][1] = MFMA(a1f, bl1, acc[1][1]);
        }
    }
    const int quad = lane >> 4;
    #pragma unroll
    for (int i = 0; i < 2; ++i) {
        #pragma unroll
        for (int j = 0; j < 2; ++j) {
            const int col = ct * 64 + wc * 32 + j * 16 + l15;
            const int m0  = rt * 64 + wr * 32 + i * 16 + quad * 4;
            const size_t base = (size_t)(b * 256 + m0) * 256 + col;
            #pragma unroll
            for (int r = 0; r < 4; ++r) {
                ushort hi, lo;
                split2(acc[i][j][r], hi, lo);
                st_u16(Yhi + base + (size_t)r * 256, hi);
                st_u16(Ylo + base + (size_t)r * 256, lo);
            }
        }
    }
}

// ---------------------------------------------------------------------------
// wact: gate GEMM (dynamic split pair x static bf16 WT) + gate epilogue
// ---------------------------------------------------------------------------
struct WAP {
    const ushort* Lhi0; const ushort* Llo0; const ushort* RT0;
    const ushort* Lhi1; const ushort* Llo1; const ushort* RT1;
    int ngemm;
    const float* bias;
    int useK6; int wxColOff;
    const float* Ax0; const float* Wx0;
    const float* h;
    float* z;
    float* hOut;
    ushort* Thi; ushort* Tlo;
    int mode;
};

__device__ void dev_wact(const WAP& p, int bid, int tid, ushort* lds) {
    ushort* Ashi = lds;
    ushort* Aslo = lds + 64 * LSTR;
    ushort* Bs   = lds + 2 * 64 * LSTR;
    int b, rt, ct;
    if (p.mode == 0) { b = bid >> 5; rt = (bid >> 3) & 3; ct = bid & 7; }
    else             { b = bid >> 4; rt = (bid >> 2) & 3; ct = bid & 3; }

    const int lane = tid & 63, wave = tid >> 6;
    const int wr = wave >> 1, wc = wave & 1;
    const int l15 = lane & 15, q8 = (lane >> 4) << 3;

    f32x4 acc[2][2];
    acc[0][0] = 0.f; acc[0][1] = 0.f; acc[1][0] = 0.f; acc[1][1] = 0.f;

    const int rr = tid >> 2, ko = (tid & 3) << 4;
    for (int g = 0; g < p.ngemm; ++g) {
        const ushort* Lh = (g ? p.Lhi1 : p.Lhi0) + (size_t)(b * 256 + rt * 64 + rr) * 256 + ko;
        const ushort* Ll = (g ? p.Llo1 : p.Llo0) + (size_t)(b * 256 + rt * 64 + rr) * 256 + ko;
        const ushort* Rt = (g ? p.RT1  : p.RT0 ) + (size_t)(ct * 64 + rr) * 256 + ko;
        ushort* wA = &Ashi[rr * LSTR + ko];
        ushort* wL = &Aslo[rr * LSTR + ko];
        ushort* wB = &Bs[rr * LSTR + ko];
        for (int k0 = 0; k0 < 256; k0 += 64) {
            unsigned long long hh[4], ll[4];
            #pragma unroll
            for (int q = 0; q < 4; ++q) hh[q] = ld_u64(Lh + k0 + 4 * q);
            #pragma unroll
            for (int q = 0; q < 4; ++q) ll[q] = ld_u64(Ll + k0 + 4 * q);
            uint4 b0v = *(const uint4*)(Rt + k0);
            uint4 b1v = *(const uint4*)(Rt + k0 + 8);
            __syncthreads();
            *(uint4*)(wB)     = b0v;
            *(uint4*)(wB + 8) = b1v;
            #pragma unroll
            for (int q = 0; q < 4; ++q) *(unsigned long long*)(wA + 4 * q) = hh[q];
            #pragma unroll
            for (int q = 0; q < 4; ++q) *(unsigned long long*)(wL + 4 * q) = ll[q];
            __syncthreads();
            #pragma unroll
            for (int sub = 0; sub < 2; ++sub) {
                const int kb = sub * 32 + q8;
                s16x8 ah0 = *(const s16x8*)&Ashi[(wr * 32 + l15) * LSTR + kb];
                s16x8 ah1 = *(const s16x8*)&Ashi[(wr * 32 + 16 + l15) * LSTR + kb];
                s16x8 al0 = *(const s16x8*)&Aslo[(wr * 32 + l15) * LSTR + kb];
                s16x8 al1 = *(const s16x8*)&Aslo[(wr * 32 + 16 + l15) * LSTR + kb];
                s16x8 b0  = *(const s16x8*)&Bs[(wc * 32 + l15) * LSTR + kb];
                s16x8 b1  = *(const s16x8*)&Bs[(wc * 32 + 16 + l15) * LSTR + kb];
                acc[0][0] = MFMA(ah0, b0, acc[0][0]);
                acc[0][0] = MFMA(al0, b0, acc[0][0]);
                acc[0][1] = MFMA(ah0, b1, acc[0][1]);
                acc[0][1] = MFMA(al0, b1, acc[0][1]);
                acc[1][0] = MFMA(ah1, b0, acc[1][0]);
                acc[1][0] = MFMA(al1, b0, acc[1][0]);
                acc[1][1] = MFMA(ah1, b1, acc[1][1]);
                acc[1][1] = MFMA(al1, b1, acc[1][1]);
            }
        }
    }

    const int quad = lane >> 4;
    const int m0base = rt * 64 + wr * 32;
    int colg[2];
    #pragma unroll
    for (int j = 0; j < 2; ++j) colg[j] = ct * 64 + wc * 32 + j * 16 + l15;
    float bv[2] = { p.bias[colg[0]], p.bias[colg[1]] };
    float v[2][2][4];
    #pragma unroll
    for (int i = 0; i < 2; ++i)
        #pragma unroll
        for (int j = 0; j < 2; ++j)
            #pragma unroll
            for (int r = 0; r < 4; ++r)
                v[i][j][r] = acc[i][j][r] + bv[j];

    if (p.useK6) {
        float w6[2][6];
        #pragma unroll
        for (int j = 0; j < 2; ++j)
            #pragma unroll
            for (int d = 0; d < 6; ++d)
                w6[j][d] = p.Wx0[d * 768 + p.wxColOff + colg[j]];
        #pragma unroll
        for (int i = 0; i < 2; ++i) {
            #pragma unroll
            for (int r = 0; r < 4; ++r) {
                int row = b * 256 + m0base + i * 16 + quad * 4 + r;
                const float* ax = p.Ax0 + (size_t)row * 8;
                float2 x01 = u64_f2(ld_u64(ax));
                float2 x23 = u64_f2(ld_u64(ax + 2));
                float2 x45 = u64_f2(ld_u64(ax + 4));
                #pragma unroll
                for (int j = 0; j < 2; ++j)
                    v[i][j][r] += x01.x * w6[j][0] + x01.y * w6[j][1] + x23.x * w6[j][2]
                                + x23.y * w6[j][3] + x45.x * w6[j][4] + x45.y * w6[j][5];
            }
        }
    }

    if (p.mode == 0) {
        if (ct < 4) {
            #pragma unroll
            for (int i = 0; i < 2; ++i)
                #pragma unroll
                for (int r = 0; r < 4; ++r) {
                    int row = b * 256 + m0base + i * 16 + quad * 4 + r;
                    #pragma unroll
                    for (int j = 0; j < 2; ++j)
                        st_f32(p.z + (size_t)row * 256 + colg[j],
                               1.f / (1.f + __expf(-v[i][j][r])));
                }
        } else {
            #pragma unroll
            for (int i = 0; i < 2; ++i) {
                int m0 = m0base + i * 16 + quad * 4;
                #pragma unroll
                for (int j = 0; j < 2; ++j) {
                    int colp = colg[j] - 256;
                    float hv[4];
                    #pragma unroll
                    for (int r = 0; r < 4; ++r)
                        hv[r] = ld_f32(p.h + (size_t)(b * 256 + m0 + r) * 256 + colp);
                    ushort hi4[4], lo4[4];
                    #pragma unroll
                    for (int r = 0; r < 4; ++r) {
                        float s = 1.f / (1.f + __expf(-v[i][j][r]));
                        split2(s * hv[r], hi4[r], lo4[r]);
                    }
                    size_t off = (size_t)b * 65536 + (size_t)colp * 256 + m0;
                    st_u64(p.Thi + off, pack4(hi4));
                    st_u64(p.Tlo + off, pack4(lo4));
                }
            }
        }
    } else {
        #pragma unroll
        for (int i = 0; i < 2; ++i) {
            int m0 = m0base + i * 16 + quad * 4;
            #pragma unroll
            for (int j = 0; j < 2; ++j) {
                float zv[4], hv[4];
                #pragma unroll
                for (int r = 0; r < 4; ++r) {
                    size_t gi = (size_t)(b * 256 + m0 + r) * 256 + colg[j];
                    zv[r] = ld_f32(p.z + gi);
                    hv[r] = ld_f32(p.h + gi);
                }
                ushort hi4[4], lo4[4];
                #pragma unroll
                for (int r = 0; r < 4; ++r) {
                    size_t gi = (size_t)(b * 256 + m0 + r) * 256 + colg[j];
                    float cc = tanhf(v[i][j][r]);
                    float hn = zv[r] * hv[r] + (1.f - zv[r]) * cc;
                    st_f32(p.hOut + gi, hn);
                    split2(hn, hi4[r], lo4[r]);
                }
                size_t off = (size_t)b * 65536 + (size_t)colg[j] * 256 + m0;
                st_u64(p.Thi + off, pack4(hi4));
                st_u64(p.Tlo + off, pack4(lo4));
            }
        }
    }
}

// ---------------------------------------------------------------------------
// Persistent kernel: whole recurrence, flag barriers between phases.
// ---------------------------------------------------------------------------
__global__ __launch_bounds__(256) void persist_kernel(Ctx c) {
    __shared__ ushort lds[3 * 64 * LSTR];
    const int tid = threadIdx.x, bid = blockIdx.x;
    unsigned gen = 0;

    // prologue: weight prep + all x-jobs (input-only dependencies)
    for (int i = bid * 256 + tid; i < 655360; i += NBLK * 256) dev_prep(i, c);
    for (int j = bid; j < 2048; j += NBLK)
        dev_xjob(j, tid, (float*)lds, ((float*)lds) + 2048, c);
    gbar(c.flags, ++gen, bid, tid);

    for (int t = 0; t < TT; ++t) {
        const float* Ax0t = c.Ax0All + (size_t)t * 16384;
        // k1: Ah0 = A@h0 (128 jobs) + head(t-1) (72 jobs)
        if (bid < 128) dev_aapply(bid, tid, lds, c.Abf, c.h0Thi, c.h0Tlo, c.AhAhi, c.AhAlo);
        else if (bid < 200 && t > 0) dev_head(bid - 128, tid, c, t - 1);
        gbar(c.flags, ++gen, bid, tid);
        // k2: z0, rh0T (256 jobs)
        { WAP p{c.AhAhi, c.AhAlo, c.WzrT0, nullptr, nullptr, nullptr, 1,
                c.b0, 1, 0, Ax0t, c.Wx0, c.h0, c.z0, nullptr, c.rhThi, c.rhTlo, 0};
          dev_wact(p, bid, tid, lds); }
        gbar(c.flags, ++gen, bid, tid);
        // k3: Arh0 = A@rh0T (128 jobs)
        if (bid < 128) dev_aapply(bid, tid, lds, c.Abf, c.rhThi, c.rhTlo, c.AhAhi, c.AhAlo);
        gbar(c.flags, ++gen, bid, tid);
        // k4: h0 update (+h0T) (128 jobs)
        if (bid < 128) {
            WAP p{c.AhAhi, c.AhAlo, c.WcT0, nullptr, nullptr, nullptr, 1,
                  c.b0 + 512, 1, 512, Ax0t, c.Wx0, c.h0, c.z0, c.h0, c.h0Thi, c.h0Tlo, 1};
            dev_wact(p, bid, tid, lds);
        }
        gbar(c.flags, ++gen, bid, tid);
        // k5: Ax1 = A@h0T (128) + Ah1 = A@h1T (128)
        if (bid < 128) dev_aapply(bid, tid, lds, c.Abf, c.h0Thi, c.h0Tlo, c.Ax1hi, c.Ax1lo);
        else dev_aapply(bid - 128, tid, lds, c.Abf, c.h1Thi, c.h1Tlo, c.AhBhi, c.AhBlo);
        gbar(c.flags, ++gen, bid, tid);
        // k6: z1, rh1T (256 jobs)
        { WAP p{c.Ax1hi, c.Ax1lo, c.WxzrT1, c.AhBhi, c.AhBlo, c.WhzrT1, 2,
                c.b1, 0, 0, Ax0t, c.Wx0, c.h1, c.z1, nullptr, c.rhThi, c.rhTlo, 0};
          dev_wact(p, bid, tid, lds); }
        gbar(c.flags, ++gen, bid, tid);
        // k7: Arh1 = A@rh1T (128 jobs)
        if (bid < 128) dev_aapply(bid, tid, lds, c.Abf, c.rhThi, c.rhTlo, c.AhBhi, c.AhBlo);
        gbar(c.flags, ++gen, bid, tid);
        // k8: h1 update (+h1T) (128 jobs)
        if (bid < 128) {
            WAP p{c.AhBhi, c.AhBlo, c.WhcT1, c.Ax1hi, c.Ax1lo, c.WxcT1, 2,
                  c.b1 + 512, 0, 0, Ax0t, c.Wx0, c.h1, c.z1, c.h1, c.h1Thi, c.h1Tlo, 1};
            dev_wact(p, bid, tid, lds);
        }
        gbar(c.flags, ++gen, bid, tid);
    }
    // final head (t = 63); last k8 barrier already passed
    if (bid < 72) dev_head(bid, tid, c, TT - 1);
}

// ---------------------------------------------------------------------------
extern "C" void kernel_launch(void* const* d_in, const int* in_sizes, int n_in,
                              void* d_out, int out_size, void* d_ws, size_t ws_size,
                              hipStream_t stream) {
    const size_t SZ = (size_t)BN * HH;   // 524288
    float* ws = (float*)d_ws;

    Ctx c;
    c.x2d  = (const float*)d_in[0];
    c.mask = (const float*)d_in[1];
    c.A    = (const float*)d_in[2];
    c.Wx0  = (const float*)d_in[3];
    c.Wh0  = (const float*)d_in[4];
    c.b0   = (const float*)d_in[5];
    c.Wx1  = (const float*)d_in[6];
    c.Wh1  = (const float*)d_in[7];
    c.b1   = (const float*)d_in[8];
    c.Wout = (const float*)d_in[9];
    c.bout = (const float*)d_in[10];
    c.out  = (float*)d_out;

    c.h0    = ws;                 // SZ
    c.h1    = ws + SZ;            // SZ
    c.h0Thi = (ushort*)(ws + 2 * SZ);
    c.h0Tlo = c.h0Thi + SZ;
    c.h1Thi = c.h0Tlo + SZ;
    c.h1Tlo = c.h1Thi + SZ;       // ends at ws + 4*SZ (float units)
    c.flags = (unsigned*)(ws + 4 * SZ);   // 256 uints
    c.z0    = ws + 4 * SZ + 256;
    c.z1    = c.z0 + SZ;
    c.Ax0All = c.z1 + SZ;         // 64 * 16384 = 2*SZ floats (4 MB)
    c.AhAhi = (ushort*)(c.Ax0All + 2 * SZ);
    c.AhAlo = c.AhAhi + SZ;
    c.AhBhi = c.AhAlo + SZ;
    c.AhBlo = c.AhBhi + SZ;
    c.Ax1hi = c.AhBlo + SZ;
    c.Ax1lo = c.Ax1hi + SZ;
    c.rhThi = c.Ax1lo + SZ;
    c.rhTlo = c.rhThi + SZ;
    c.Abf   = c.rhTlo + SZ;       // 65536
    c.WzrT0 = c.Abf + 65536;      // 131072
    c.WcT0  = c.WzrT0 + 131072;   // 65536
    c.WxzrT1 = c.WcT0 + 65536;    // 131072
    c.WhzrT1 = c.WxzrT1 + 131072; // 131072
    c.WxcT1  = c.WhzrT1 + 131072; // 65536
    c.WhcT1  = c.WxcT1 + 65536;   // 65536

    // zero h0,h1 (fp32), h0T/h1T split pairs (bf16 zero = 0), barrier flags
    hipMemsetAsync(ws, 0, (4 * SZ + 256) * sizeof(float), stream);

    persist_kernel<<<dim3(NBLK), dim3(256), 0, stream>>>(c);
}